// Round 9
// baseline (258.600 us; speedup 1.0000x reference)
//
#include <hip/hip_runtime.h>
#include <hip/hip_bf16.h>

#define D_ 128
#define E_ 100
#define K_ 4
#define C_ 400
#define NCHUNK 128     // atom chunks in k_sums2 (x2 dim-halves = 256 blocks)

// ws layout (f32 slots):
//   [0, 51200)        sums f32[C][D]
//   [51200, 51600)    countsF f32[C]
//   [51600]           loss f32
//   [51712, +256*25600)  psum: per-block [400][64] partials (partials path)
//   [OFF_PCNT, +128*400) pcnt: per-chunk counts partials
#define OFF_COUNTS 51200
#define OFF_LOSS   51600
#define OFF_PSUM   51712
#define PSUM_SZ    (256 * C_ * 64)          // 6,553,600 floats
#define OFF_PCNT   (OFF_PSUM + PSUM_SZ)
#define WS_NEED_PART ((size_t)(OFF_PCNT + NCHUNK * C_) * 4)

// Kernel 1: streaming per-atom argmin (round-3-proven structure).
// 16 lanes per atom, 8 contiguous floats per lane; codebook rows from L1.
__global__ __launch_bounds__(256) void k_assign(
    const float* __restrict__ h, const int* __restrict__ ei,
    const float* __restrict__ cb, float* __restrict__ hq,
    float* __restrict__ at, float* __restrict__ loss_acc, int N) {
  const int lane16 = threadIdx.x & 15;
  const int gid0 = (blockIdx.x * blockDim.x + threadIdx.x) >> 4;
  const int ngroups = (gridDim.x * blockDim.x) >> 4;
  float loss = 0.f;
  for (int a = gid0; a < N; a += ngroups) {
    const float* hrow = h + (size_t)a * D_ + lane16 * 8;
    float4 h0 = reinterpret_cast<const float4*>(hrow)[0];
    float4 h1 = reinterpret_cast<const float4*>(hrow)[1];
    int e = ei[a];
    const float* cbase = cb + (size_t)e * (K_ * D_);
    float p[4];
#pragma unroll
    for (int j = 0; j < 4; ++j) {
      const float* cr = cbase + j * D_ + lane16 * 8;
      float4 c0 = reinterpret_cast<const float4*>(cr)[0];
      float4 c1 = reinterpret_cast<const float4*>(cr)[1];
      float d0 = h0.x - c0.x, d1 = h0.y - c0.y;
      float d2 = h0.z - c0.z, d3 = h0.w - c0.w;
      float d4 = h1.x - c1.x, d5 = h1.y - c1.y;
      float d6 = h1.z - c1.z, d7 = h1.w - c1.w;
      p[j] = ((d0*d0 + d1*d1) + (d2*d2 + d3*d3)) +
             ((d4*d4 + d5*d5) + (d6*d6 + d7*d7));
    }
#pragma unroll
    for (int s = 1; s < 16; s <<= 1) {
#pragma unroll
      for (int j = 0; j < 4; ++j) p[j] += __shfl_xor(p[j], s, 64);
    }
    float bp = p[0]; int best = 0;
    if (p[1] < bp) { bp = p[1]; best = 1; }
    if (p[2] < bp) { bp = p[2]; best = 2; }
    if (p[3] < bp) { bp = p[3]; best = 3; }
    const float* br = cbase + best * D_ + lane16 * 8;
    float4 b0 = reinterpret_cast<const float4*>(br)[0];
    float4 b1 = reinterpret_cast<const float4*>(br)[1];
    float* orow = hq + (size_t)a * D_ + lane16 * 8;
    reinterpret_cast<float4*>(orow)[0] = b0;
    reinterpret_cast<float4*>(orow)[1] = b1;
    if (lane16 == 0) {
      at[a] = (float)(e * K_ + best);
      loss += bp;
    }
  }
  __shared__ float bl;
  if (threadIdx.x == 0) bl = 0.f;
  __syncthreads();
  if (lane16 == 0) unsafeAtomicAdd(&bl, loss);
  __syncthreads();
  if (threadIdx.x == 0) unsafeAtomicAdd(loss_acc, bl);
}

// Kernel 2: streaming segment-sum + counts. Block = (chunk, dim-half).
// LDS acc[400][64]; per atom 4 x ds_add_f32 with per-group rotated
// component order (disjoint bank residues across the 4 groups).
__global__ __launch_bounds__(1024) void k_sums2(
    const float* __restrict__ h, const float* __restrict__ at,
    float* __restrict__ sums, float* __restrict__ countsF,
    float* __restrict__ psum, float* __restrict__ pcnt,
    int dopart, int N) {
  const int half = blockIdx.x & 1;
  const int chunk = blockIdx.x >> 1;
  __shared__ float acc[C_ * 64];
  __shared__ float cnt[C_];
  for (int i = threadIdx.x; i < C_ * 64; i += 1024) acc[i] = 0.f;
  if (half == 0)
    for (int i = threadIdx.x; i < C_; i += 1024) cnt[i] = 0.f;
  __syncthreads();

  const int per = (N + NCHUNK - 1) / NCHUNK;
  const int a0 = chunk * per;
  const int a1 = min(a0 + per, N);
  const int w = threadIdx.x >> 6;
  const int lane = threadIdx.x & 63;
  const int g = lane >> 4, t = lane & 15;
  const float4* h4 = (const float4*)h;

  int a = a0 + w * 4 + g;
  float4 v = {}; int code = 0;
  bool act = a < a1;
  if (act) { v = h4[(size_t)a * 32 + half * 16 + t]; code = (int)at[a]; }
  while (act) {
    int an = a + 64;
    bool actn = an < a1;
    float4 vn = {}; int cn = 0;
    if (actn) { vn = h4[(size_t)an * 32 + half * 16 + t]; cn = (int)at[an]; }

    float* ap = &acc[code * 64 + t * 4];
    float comp[4] = { v.x, v.y, v.z, v.w };
#pragma unroll
    for (int k = 0; k < 4; ++k) {
      int kk = (k + g) & 3;
      unsafeAtomicAdd(&ap[kk], comp[kk]);
    }
    if (half == 0 && t == 0) unsafeAtomicAdd(&cnt[code], 1.f);

    a = an; act = actn; v = vn; code = cn;
  }
  __syncthreads();

  if (dopart) {
    float* pb = psum + (size_t)blockIdx.x * (C_ * 64);
    for (int i = threadIdx.x; i < C_ * 64; i += 1024) pb[i] = acc[i];
    if (half == 0) {
      float* pc = pcnt + (size_t)chunk * C_;
      for (int i = threadIdx.x; i < C_; i += 1024) pc[i] = cnt[i];
    }
  } else {
    for (int i = threadIdx.x; i < C_ * 64; i += 1024) {
      float vv = acc[i];
      if (vv != 0.f)
        unsafeAtomicAdd(&sums[(size_t)(i >> 6) * D_ + half * 64 + (i & 63)], vv);
    }
    if (half == 0)
      for (int i = threadIdx.x; i < C_; i += 1024)
        if (cnt[i] != 0.f) unsafeAtomicAdd(&countsF[i], cnt[i]);
  }
}

// Kernel 3 (partials path): reduce per-block partials -> sums, countsF.
__global__ __launch_bounds__(256) void k_reduce(
    const float* __restrict__ psum, const float* __restrict__ pcnt,
    float* __restrict__ sums, float* __restrict__ countsF) {
  int idx = blockIdx.x * 256 + threadIdx.x;
  if (idx < C_ * D_) {
    int code = idx >> 7;
    int dim = idx & 127;
    int half = dim >> 6;
    int dl = dim & 63;
    const float* p = psum + (size_t)half * (C_ * 64) + code * 64 + dl;
    float s = 0.f;
    for (int b = 0; b < NCHUNK; ++b)
      s += p[(size_t)b * 2 * (C_ * 64)];
    sums[idx] = s;
  }
  if (idx < C_) {
    float s = 0.f;
    for (int b = 0; b < NCHUNK; ++b)
      s += pcnt[(size_t)b * C_ + idx];
    countsF[idx] = s;
  }
}

// Kernel 4: EMA finalize + loss scalar.
__global__ __launch_bounds__(256) void k_final(
    const float* __restrict__ cb, const float* __restrict__ ecnt,
    const float* __restrict__ esum, const float* __restrict__ ws,
    float* __restrict__ out, int N) {
  const float* sums = ws;
  const float* countsF = ws + OFF_COUNTS;
  int idx = blockIdx.x * 256 + threadIdx.x;
  const size_t base = (size_t)N * D_ + N + 1;
  if (idx < C_ * D_) {
    int c = idx >> 7;
    int e4 = (c >> 2) << 2;
    bool present = (countsF[e4] + countsF[e4 + 1] + countsF[e4 + 2] + countsF[e4 + 3]) > 0.f;
    float es = esum[idx];
    float s  = sums[idx];
    float ns = present ? 0.99f * es + 0.01f * s : es;
    float ec = ecnt[c];
    float nc = present ? 0.99f * ec + 0.01f * countsF[c] : ec;
    float ncbv = present ? ns / fmaxf(nc, 1e-5f) : cb[idx];
    out[base + idx] = ncbv;
    if ((idx & 127) == 0) out[base + C_ * D_ + c] = nc;
    out[base + C_ * D_ + C_ + idx] = ns;
  }
  if (idx == 0) {
    float loss = ws[OFF_LOSS];
    out[(size_t)N * D_ + N] = 0.25f * loss / ((float)N * (float)D_);
  }
}

extern "C" void kernel_launch(void* const* d_in, const int* in_sizes, int n_in,
                              void* d_out, int out_size, void* d_ws, size_t ws_size,
                              hipStream_t stream) {
  // Identify inputs by size (robust to input-order changes).
  const float* h = nullptr; const int* ei = nullptr;
  const float* cb = nullptr; const float* ecnt = nullptr; const float* esum = nullptr;
  long hsz = -1; int hidx = -1;
  for (int i = 0; i < n_in; ++i)
    if ((long)in_sizes[i] > hsz) { hsz = in_sizes[i]; hidx = i; }
  h = (const float*)d_in[hidx];
  const int N = (int)(hsz / D_);
  for (int i = 0; i < n_in; ++i) {
    if (i == hidx) continue;
    const int s = in_sizes[i];
    if (s == N) ei = (const int*)d_in[i];
    else if (s == C_) ecnt = (const float*)d_in[i];
    else if (s == C_ * D_) { if (!cb) cb = (const float*)d_in[i]; else esum = (const float*)d_in[i]; }
  }

  float* out = (float*)d_out;
  float* hq  = out;
  float* at  = out + (size_t)N * D_;

  float* ws = (float*)d_ws;
  float* sums    = ws;
  float* countsF = ws + OFF_COUNTS;
  float* lossp   = ws + OFF_LOSS;
  float* psum    = ws + OFF_PSUM;
  float* pcnt    = ws + OFF_PCNT;

  const int dopart = (ws_size >= WS_NEED_PART) ? 1 : 0;

  // zero sums/countsF/loss (~206 KB)
  hipMemsetAsync(d_ws, 0, (size_t)(OFF_LOSS + 1) * 4, stream);

  k_assign<<<2048, 256, 0, stream>>>(h, ei, cb, hq, at, lossp, N);
  k_sums2<<<NCHUNK * 2, 1024, 0, stream>>>(h, at, sums, countsF,
                                           psum, pcnt, dopart, N);
  if (dopart)
    k_reduce<<<(C_ * D_ + 255) / 256, 256, 0, stream>>>(psum, pcnt, sums, countsF);
  k_final<<<(C_ * D_ + 255) / 256, 256, 0, stream>>>(cb, ecnt, esum, ws, out, N);
}